// Round 14
// baseline (192.615 us; speedup 1.0000x reference)
//
#include <hip/hip_runtime.h>
#include <hip/hip_bf16.h>
#include <cstdint>

#define BB 128
#define TT 1024
#define DD 256
#define NN 64
#define SCALE 0.0625f   // 1/sqrt(256)

using u16 = unsigned short;
using u32 = unsigned int;

typedef __attribute__((ext_vector_type(8))) short bf16x8;
typedef __attribute__((ext_vector_type(4))) float f32x4;

typedef const __attribute__((address_space(1))) u32 gbl_u32;
typedef __attribute__((address_space(3))) u32 lds_u32;

__device__ __forceinline__ u16 f2bf(float f) {
  u32 u = __float_as_uint(f);
  u32 r = (u + 0x7fffu + ((u >> 16) & 1u)) >> 16;  // RNE
  return (u16)r;
}

// async 16B global->LDS. LDS base must be wave-uniform; lane i lands at +i*16.
__device__ __forceinline__ void gload16(const void* g, void* l) {
  __builtin_amdgcn_global_load_lds((gbl_u32*)g, (lds_u32*)l, 16, 0, 0);
}

// ---- K0: prep0 — coalesced transposes + mask scan + bco.
__global__ __launch_bounds__(256) void prep0(
    const float* __restrict__ masks, const float* __restrict__ Wq,
    const float* __restrict__ Wc, const float* __restrict__ Wo,
    const float* __restrict__ bc,
    float* __restrict__ WqT, float* __restrict__ WcTf, u16* __restrict__ WcTb,
    float* __restrict__ bco, int* __restrict__ r, int* __restrict__ Rfin,
    float* __restrict__ ptr_out) {
  __shared__ __align__(16) float lds[64 * 65];
  const int bid = blockIdx.x;
  const int tid = threadIdx.x;

  if (bid < 128) {  // mask scan
    int* sm = (int*)lds;
    int b = bid;
    int t4 = tid * 4;
    int v[4], pm[4];
#pragma unroll
    for (int j = 0; j < 4; ++j) {
      float m = masks[b * TT + t4 + j];
      v[j] = (m == 0.0f) ? (t4 + j) : 0;
    }
    pm[0] = v[0];
    pm[1] = max(pm[0], v[1]);
    pm[2] = max(pm[1], v[2]);
    pm[3] = max(pm[2], v[3]);
    sm[tid] = pm[3];
    __syncthreads();
    for (int off = 1; off < 256; off <<= 1) {
      int u = (tid >= off) ? sm[tid - off] : 0;
      __syncthreads();
      sm[tid] = max(sm[tid], u);
      __syncthreads();
    }
    int excl = (tid > 0) ? sm[tid - 1] : 0;
#pragma unroll
    for (int j = 0; j < 4; ++j) r[b * TT + t4 + j] = max(excl, pm[j]);
    if (tid == 255) {
      int R = max(excl, pm[3]);
      Rfin[b] = R;
      ptr_out[b] = (float)((TT - R) & (NN - 1));
    }
    return;
  }

  if (bid < 160) {  // transpose tiles
    int t = bid - 128;
    int mat = t >> 4;          // 0: Wq, 1: Wc
    int tile = t & 15;
    int R0 = (tile >> 2) * 64, C0 = (tile & 3) * 64;
    const float* src = (mat == 0) ? Wq : Wc;
#pragma unroll
    for (int i = 0; i < 4; ++i) {
      int idx = i * 256 + tid;
      int row = idx >> 4, cu = (idx & 15) << 2;
      float4 v = *(const float4*)(src + (size_t)(R0 + row) * 256 + C0 + cu);
      *(float4*)(lds + row * 65 + cu) = v;
    }
    __syncthreads();
#pragma unroll
    for (int i = 0; i < 4; ++i) {
      int idx = i * 256 + tid;
      int col = idx >> 4, ru = (idx & 15) << 2;
      float4 o;
      o.x = lds[(ru + 0) * 65 + col];
      o.y = lds[(ru + 1) * 65 + col];
      o.z = lds[(ru + 2) * 65 + col];
      o.w = lds[(ru + 3) * 65 + col];
      size_t dsti = (size_t)(C0 + col) * 256 + R0 + ru;
      if (mat == 0) {
        *(float4*)(WqT + dsti) = o;
      } else {
        *(float4*)(WcTf + dsti) = o;
        ushort4 p;
        p.x = f2bf(o.x); p.y = f2bf(o.y); p.z = f2bf(o.z); p.w = f2bf(o.w);
        *(ushort4*)(WcTb + dsti) = p;
      }
    }
    return;
  }

  {  // bco
    int k = tid;
    float acc = 0.f;
    for (int d = 0; d < 256; ++d)
      acc = fmaf(bc[d], Wo[d * 256 + k], acc);
    bco[k] = acc;
  }
}

// ---- K1: front2 — weight GEMMs (coalesced VALU) + h2bf.
__global__ __launch_bounds__(256) void front2(
    const float* __restrict__ H, const float* __restrict__ Wc,
    const float* __restrict__ Wo, const float* __restrict__ WqT,
    const float* __restrict__ WcTf, u16* __restrict__ Hb,
    u16* __restrict__ WT) {
  const int bid = blockIdx.x;
  const int tid = threadIdx.x;

  if (bid < 256) {  // Gt row n
    int n = bid, k = tid;
    float a0 = 0.f, a1 = 0.f, a2 = 0.f, a3 = 0.f;
    for (int d = 0; d < 256; d += 4) {
      float4 wv = *(const float4*)(Wc + n * 256 + d);  // wave-uniform
      a0 = fmaf(wv.x, WqT[(size_t)(d + 0) * 256 + k], a0);
      a1 = fmaf(wv.y, WqT[(size_t)(d + 1) * 256 + k], a1);
      a2 = fmaf(wv.z, WqT[(size_t)(d + 2) * 256 + k], a2);
      a3 = fmaf(wv.w, WqT[(size_t)(d + 3) * 256 + k], a3);
    }
    WT[(size_t)n * 256 + k] = f2bf((a0 + a1) + (a2 + a3));
    return;
  }

  if (bid < 512) {  // WcoT row n
    int n = bid - 256, k = tid;
    float a0 = 0.f, a1 = 0.f, a2 = 0.f, a3 = 0.f;
    for (int d = 0; d < 256; d += 4) {
      float w0 = Wo[(size_t)(d + 0) * 256 + n];  // wave-uniform scalars
      float w1 = Wo[(size_t)(d + 1) * 256 + n];
      float w2 = Wo[(size_t)(d + 2) * 256 + n];
      float w3 = Wo[(size_t)(d + 3) * 256 + n];
      a0 = fmaf(w0, WcTf[(size_t)(d + 0) * 256 + k], a0);
      a1 = fmaf(w1, WcTf[(size_t)(d + 1) * 256 + k], a1);
      a2 = fmaf(w2, WcTf[(size_t)(d + 2) * 256 + k], a2);
      a3 = fmaf(w3, WcTf[(size_t)(d + 3) * 256 + k], a3);
    }
    WT[(size_t)(256 + n) * 256 + k] = f2bf((a0 + a1) + (a2 + a3));
    return;
  }

  {  // h2bf: 128 rows/block
    size_t base = (size_t)(bid - 512) * 128 * 256;
#pragma unroll
    for (int i = 0; i < 16; ++i) {
      size_t e = base + ((size_t)(i * 256 + tid)) * 8;
      float4 a = *(const float4*)(H + e);
      float4 b = *(const float4*)(H + e + 4);
      uint4 p;
      p.x = (u32)f2bf(a.x) | ((u32)f2bf(a.y) << 16);
      p.y = (u32)f2bf(a.z) | ((u32)f2bf(a.w) << 16);
      p.z = (u32)f2bf(b.x) | ((u32)f2bf(b.y) << 16);
      p.w = (u32)f2bf(b.z) | ((u32)f2bf(b.w) << 16);
      *(uint4*)(Hb + e) = p;
    }
  }
}

// ---- K2: MFMA GEMM, BM=64, T3+T4 2-phase pipeline (m248v2 recipe):
// double-buffered LDS (80KB, 2 blocks/CU), stage(kt+1) issued BEFORE
// computing kt, counted s_waitcnt vmcnt(10) (10 = loads/thread/tile) so
// the next tile's loads stay in flight across the barrier — never a full
// drain in the main loop. Raw s_barrier + sched_barrier fences (rule #18).
__global__ __launch_bounds__(256, 2) void gemm2(
    const u16* __restrict__ Hb, const u16* __restrict__ WT,
    const float* __restrict__ bco,
    u16* __restrict__ HG, u16* __restrict__ CWT) {
  __shared__ __align__(16) char smem[81920];
  // buffers: As[sel] 8KB each at 0/8192; Bs[sel] 32KB each at 16384/49152
  const int tid = threadIdx.x;
  const int bid = blockIdx.x;
  const int chunk = bid >> 4, jj8 = bid & 15;
  const int xb = chunk * 8 + (jj8 & 7);   // 0..2047
  const int ntb = jj8 >> 3;
  const int M0 = xb * 64;
  const int N0 = ntb * 256;
  const int w = tid >> 6, l = tid & 63;
  const int l15 = l & 15, g = l >> 4;

  // stage tile kt into buffer sel: 8 B-loads + 2 A-loads per thread
  auto STAGE = [&](int kt, int sel) {
    u16* Bsd = (u16*)(smem + 16384 + sel * 32768);
    u16* Asd = (u16*)(smem + sel * 8192);
#pragma unroll
    for (int i = 0; i < 8; ++i) {
      int q = i * 256 + w * 64 + l;
      int n = q >> 3, u = q & 7;
      const u16* src = WT + (size_t)(N0 + n) * 256 + kt * 64 + ((u ^ (n & 7)) << 3);
      gload16(src, Bsd + (size_t)(i * 256 + w * 64) * 8);
    }
#pragma unroll
    for (int i = 0; i < 2; ++i) {
      int q = i * 256 + w * 64 + l;
      int row = q >> 3, u = q & 7;
      const u16* src = Hb + (size_t)(M0 + row) * 256 + kt * 64 + ((u ^ (row & 7)) << 3);
      gload16(src, Asd + (size_t)(i * 256 + w * 64) * 8);
    }
  };

  f32x4 acc[4][4];
#pragma unroll
  for (int i = 0; i < 4; ++i)
#pragma unroll
    for (int j = 0; j < 4; ++j) acc[i][j] = f32x4{0.f, 0.f, 0.f, 0.f};

  STAGE(0, 0);  // prologue

#pragma unroll
  for (int kt = 0; kt < 4; ++kt) {
    const int sel = kt & 1;
    if (kt < 3) {
      STAGE(kt + 1, sel ^ 1);
      asm volatile("s_waitcnt vmcnt(10)" ::: "memory");  // only tile kt's loads
    } else {
      asm volatile("s_waitcnt vmcnt(0)" ::: "memory");
    }
    __builtin_amdgcn_sched_barrier(0);
    __builtin_amdgcn_s_barrier();   // all waves: tile kt resident
    __builtin_amdgcn_sched_barrier(0);
    {
      u16* As = (u16*)(smem + sel * 8192);
      u16* Bs = (u16*)(smem + 16384 + sel * 32768);
#pragma unroll
      for (int ks = 0; ks < 2; ++ks) {
        bf16x8 af[4];
#pragma unroll
        for (int mt = 0; mt < 4; ++mt) {
          int row = mt * 16 + l15;
          int unit = ks * 4 + g;
          af[mt] = *(const bf16x8*)(As + row * 64 + ((unit ^ (row & 7)) << 3));
        }
#pragma unroll
        for (int nt = 0; nt < 4; ++nt) {
          int n = w * 64 + nt * 16 + l15;
          int unit = ks * 4 + g;
          bf16x8 bfr = *(const bf16x8*)(Bs + n * 64 + ((unit ^ (n & 7)) << 3));
#pragma unroll
          for (int mt = 0; mt < 4; ++mt)
            acc[mt][nt] = __builtin_amdgcn_mfma_f32_16x16x32_bf16(af[mt], bfr, acc[mt][nt], 0, 0, 0);
        }
      }
    }
    __builtin_amdgcn_sched_barrier(0);
    __builtin_amdgcn_s_barrier();   // readers of buf[sel] done before overwrite
  }
  __syncthreads();  // before smem reuse in epilogue

  if (ntb == 0) {
    // bf16 bounce [64][264] (stride 264 > 256: alias-free; rows 16B-aligned).
    u16* ep16 = (u16*)smem;
#pragma unroll
    for (int mt = 0; mt < 4; ++mt)
#pragma unroll
      for (int nt = 0; nt < 4; ++nt) {
        int row = mt * 16 + g * 4;
        int col = w * 64 + nt * 16 + l15;
#pragma unroll
        for (int rg = 0; rg < 4; ++rg)
          ep16[(row + rg) * 264 + col] = f2bf(acc[mt][nt][rg]);
      }
    __syncthreads();
#pragma unroll
    for (int i = 0; i < 8; ++i) {
      int c = tid + i * 256;
      int row = c >> 5, c8 = (c & 31) << 3;   // 64 rows x 32 8-elem units
      uint4 pk = *(const uint4*)(ep16 + row * 264 + c8);
      *(uint4*)(HG + (size_t)(M0 + row) * 256 + c8) = pk;
    }
  } else {
    // transposed bounce [256][66] (stride 66 > 64: alias-free)
    u16* epT = (u16*)smem;
    float bcv[4];
#pragma unroll
    for (int nt = 0; nt < 4; ++nt) bcv[nt] = bco[w * 64 + nt * 16 + l15];
#pragma unroll
    for (int mt = 0; mt < 4; ++mt)
#pragma unroll
      for (int nt = 0; nt < 4; ++nt) {
        int d = w * 64 + nt * 16 + l15;
        int m = mt * 16 + g * 4;
#pragma unroll
        for (int rg = 0; rg < 4; ++rg)
          epT[d * 66 + m + rg] = f2bf(acc[mt][nt][rg] + bcv[nt]);
      }
    __syncthreads();
    int ml = tid & 63, dg = tid >> 6;
    for (int d = dg; d < 256; d += 4) {
      CWT[(size_t)d * 131072 + M0 + ml] = epT[d * 66 + ml];
    }
  }
}

// ---- K3: MFMA sliding-window attention (blocks 0..2047) + final-buffer
// MFMA (tail blocks 2048..2175). R10/R12-proven version.
__global__ __launch_bounds__(256, 3) void attn_mfma(
    const u16* __restrict__ HGp, const u16* __restrict__ Hbp,
    const u16* __restrict__ CWTp, const int* __restrict__ r,
    const float* __restrict__ bo, float* __restrict__ out,
    const u16* __restrict__ Hb0, const u16* __restrict__ WcT,
    const float* __restrict__ bc, const int* __restrict__ Rfin,
    float* __restrict__ outbuf) {
  extern __shared__ __align__(16) char smem[];
  const int bid0 = blockIdx.x;
  const int tid = threadIdx.x;
  const int l = tid & 63, w = tid >> 6;
  const int l15 = l & 15, g = l >> 4;

  if (bid0 >= 2048) {
    // ---------- buf path: buf[b][m][d] = valid ? Hb[t_m]@Wc + bc : 0 ----------
    u16* As_b = (u16*)smem;
    u16* Bs_b = (u16*)(smem + 8192);
    const int b = bid0 - 2048;
    const int R = Rfin[b];

    f32x4 acc[4][4];
#pragma unroll
    for (int i = 0; i < 4; ++i)
#pragma unroll
      for (int j = 0; j < 4; ++j) acc[i][j] = f32x4{0.f, 0.f, 0.f, 0.f};

    for (int kt = 0; kt < 4; ++kt) {
      __syncthreads();
#pragma unroll
      for (int i = 0; i < 2; ++i) {
        int c = tid + i * 256;
        int row = c >> 3, u = c & 7;
        int rem = (TT - 1) - R - row;
        uint4 v = {0, 0, 0, 0};
        if (rem >= 0) {
          int tn = R + row + ((rem >> 6) << 6);
          v = *(const uint4*)(Hb0 + ((size_t)b * TT + tn) * 256 + kt * 64 +
                              ((u ^ (row & 7)) << 3));
        }
        *(uint4*)(As_b + row * 64 + (u << 3)) = v;
      }
#pragma unroll
      for (int i = 0; i < 8; ++i) {
        int c = tid + i * 256;
        int n = c >> 3, u = c & 7;
        uint4 v = *(const uint4*)(WcT + (size_t)n * 256 + kt * 64 + u * 8);
        *(uint4*)(Bs_b + n * 64 + ((u ^ (n & 7)) << 3)) = v;
      }
      __syncthreads();
#pragma unroll
      for (int ks = 0; ks < 2; ++ks) {
        bf16x8 af[4];
#pragma unroll
        for (int mt = 0; mt < 4; ++mt) {
          int row = mt * 16 + l15;
          int unit = ks * 4 + g;
          af[mt] = *(const bf16x8*)(As_b + row * 64 + ((unit ^ (row & 7)) << 3));
        }
#pragma unroll
        for (int nt = 0; nt < 4; ++nt) {
          int n = w * 64 + nt * 16 + l15;
          int unit = ks * 4 + g;
          bf16x8 bfr = *(const bf16x8*)(Bs_b + n * 64 + ((unit ^ (n & 7)) << 3));
#pragma unroll
          for (int mt = 0; mt < 4; ++mt)
            acc[mt][nt] = __builtin_amdgcn_mfma_f32_16x16x32_bf16(af[mt], bfr, acc[mt][nt], 0, 0, 0);
        }
      }
    }

    float bc4[4];
#pragma unroll
    for (int nt = 0; nt < 4; ++nt) bc4[nt] = bc[w * 64 + nt * 16 + l15];
#pragma unroll
    for (int mt = 0; mt < 4; ++mt) {
#pragma unroll
      for (int rg = 0; rg < 4; ++rg) {
        int m = mt * 16 + g * 4 + rg;
        bool valid = ((TT - 1) - R - m) >= 0;
#pragma unroll
        for (int nt = 0; nt < 4; ++nt) {
          int d = w * 64 + nt * 16 + l15;
          float val = valid ? (acc[mt][nt][rg] + bc4[nt]) : 0.0f;
          outbuf[((size_t)b * NN + m) * DD + d] = val;
        }
      }
    }
    return;
  }

  // ---------- attention path ----------
  u16* reg0 = (u16*)smem;              // [128][136] staging / ob f32[64][132]
  u16* qs = (u16*)(smem + 34816);      // [64][136]; P overlays Q after scores
  u16* ps = qs;
  int* rvs = (int*)(smem + 52224);     // [64]
  // XCD swizzle (T1): each XCD gets 256 consecutive work ids = 16 full batches.
  const int bid = (bid0 & 7) * 256 + (bid0 >> 3);
  const int b = bid >> 4;
  const int t0 = (bid & 15) * 64;
  const long bt = (long)b * TT;

  if (tid < 64) rvs[tid] = r[bt + t0 + tid];

  f32x4 accs[8];
#pragma unroll
  for (int mt = 0; mt < 8; ++mt) accs[mt] = f32x4{0.f, 0.f, 0.f, 0.f};

  for (int kp = 0; kp < 2; ++kp) {
    __syncthreads();
#pragma unroll
    for (int i = 0; i < 8; ++i) {
      int c = tid + i * 256;
      int row = c >> 4, u = c & 15;
      long tp = bt + (t0 - 64 + row);
      uint4 v = *(const uint4*)(Hbp + tp * 256 + kp * 128 + u * 8);
      *(uint4*)(reg0 + row * 136 + u * 8) = v;
    }
#pragma unroll
    for (int i = 0; i < 4; ++i) {
      int c = tid + i * 256;
      int row = c >> 4, u = c & 15;
      uint4 v = *(const uint4*)(HGp + (bt + t0 + row) * 256 + kp * 128 + u * 8);
      *(uint4*)(qs + row * 136 + u * 8) = v;
    }
    __syncthreads();
    __builtin_amdgcn_s_setprio(1);
#pragma unroll
    for (int ks = 0; ks < 4; ++ks) {
      int qrow = w * 16 + l15;
      bf16x8 bq_ = *(const bf16x8*)(qs + qrow * 136 + ks * 32 + g * 8);
#pragma unroll
      for (int mt = 0; mt < 8; ++mt) {
        int crow = mt * 16 + l15;
        bf16x8 ac = *(const bf16x8*)(reg0 + crow * 136 + ks * 32 + g * 8);
        accs[mt] = __builtin_amdgcn_mfma_f32_16x16x32_bf16(ac, bq_, accs[mt], 0, 0, 0);
      }
    }
    __builtin_amdgcn_s_setprio(0);
  }
  __syncthreads();

  const int jj = w * 16 + l15;
  const int rv = rvs[jj];
  const int ibase = g * 4;
  float mx = -3.0e38f;
#pragma unroll
  for (int mt = 0; mt < 8; ++mt) {
#pragma unroll
    for (int rg = 0; rg < 4; ++rg) {
      int i = mt * 16 + ibase + rg;
      int u = i - jj;
      float s;
      if (u >= 0 && u < 64)
        s = ((t0 - 64 + i) >= rv) ? accs[mt][rg] * SCALE : 0.0f;
      else
        s = -3.0e38f;
      accs[mt][rg] = s;
      mx = fmaxf(mx, s);
    }
  }
  mx = fmaxf(mx, __shfl_xor(mx, 16));
  mx = fmaxf(mx, __shfl_xor(mx, 32));
  float den = 0.f;
#pragma unroll
  for (int mt = 0; mt < 8; ++mt) {
#pragma unroll
    for (int rg = 0; rg < 4; ++rg) {
      float s = accs[mt][rg];
      float e = (s > -1.0e37f) ? __expf(s - mx) : 0.0f;
      accs[mt][rg] = e;
      den += e;
    }
  }
  den += __shfl_xor(den, 16);
  den += __shfl_xor(den, 32);
  float inv = 1.0f / den;
#pragma unroll
  for (int mt = 0; mt < 8; ++mt) {
    float wv[4];
#pragma unroll
    for (int rg = 0; rg < 4; ++rg) {
      int i = mt * 16 + ibase + rg;
      int u = i - jj;
      bool ok = (u >= 0) && (u < 64) && ((t0 - 64 + i) >= rv);
      wv[rg] = ok ? accs[mt][rg] * inv : 0.0f;
    }
    u32 p0 = (u32)f2bf(wv[0]) | ((u32)f2bf(wv[1]) << 16);
    u32 p1 = (u32)f2bf(wv[2]) | ((u32)f2bf(wv[3]) << 16);
    *(uint2*)(ps + (size_t)jj * 136 + mt * 16 + ibase) = make_uint2(p0, p1);
  }
  __syncthreads();

  float* ob = (float*)reg0;
  for (int dp = 0; dp < 2; ++dp) {
#pragma unroll
    for (int i = 0; i < 8; ++i) {
      int c = tid + i * 256;
      int dl = c >> 4, u = c & 15;
      long tp = bt + (t0 - 64 + u * 8);
      uint4 v = *(const uint4*)(CWTp + (long)(dp * 128 + dl) * 131072 + tp);
      *(uint4*)(reg0 + dl * 136 + u * 8) = v;
    }
    __syncthreads();
    f32x4 accp[8];
#pragma unroll
    for (int mt = 0; mt < 8; ++mt) accp[mt] = f32x4{0.f, 0.f, 0.f, 0.f};
    __builtin_amdgcn_s_setprio(1);
#pragma unroll
    for (int ks = 0; ks < 4; ++ks) {
      bf16x8 bp = *(const bf16x8*)(ps + (size_t)(w * 16 + l15) * 136 + ks * 32 + g * 8);
#pragma unroll
      for (int mt = 0; mt < 8; ++mt) {
        bf16x8 av = *(const bf16x8*)(reg0 + (mt * 16 + l15) * 136 + ks * 32 + g * 8);
        accp[mt] = __builtin_amdgcn_mfma_f32_16x16x32_bf16(av, bp, accp[mt], 0, 0, 0);
      }
    }
    __builtin_amdgcn_s_setprio(0);
    __syncthreads();
#pragma unroll
    for (int mt = 0; mt < 8; ++mt) {
      int d0 = mt * 16 + g * 4;
      *(f32x4*)(ob + (size_t)jj * 132 + d0) = accp[mt];
    }
    __syncthreads();
#pragma unroll
    for (int i = 0; i < 8; ++i) {
      int c = tid + i * 256;
      int row = c >> 5, cq = (c & 31) << 2;
      float4 v = *(const float4*)(ob + row * 132 + cq);
      float4 b4 = *(const float4*)(bo + dp * 128 + cq);
      v.x += b4.x; v.y += b4.y; v.z += b4.z; v.w += b4.w;
      *(float4*)(out + (bt + t0 + row) * 256 + dp * 128 + cq) = v;
    }
    __syncthreads();
  }
}

extern "C" void kernel_launch(void* const* d_in, const int* in_sizes, int n_in,
                              void* d_out, int out_size, void* d_ws, size_t ws_size,
                              hipStream_t stream) {
  const float* H = (const float*)d_in[0];
  const float* masks = (const float*)d_in[1];
  const float* Wq = (const float*)d_in[3];
  const float* Wo = (const float*)d_in[5];
  const float* bo = (const float*)d_in[6];
  const float* Wc = (const float*)d_in[7];
  const float* bc = (const float*)d_in[8];

  float* out = (float*)d_out;
  float* out_read = out;
  float* out_buf = out + (size_t)BB * TT * DD;
  float* out_ptr = out_buf + (size_t)BB * NN * DD;

  char* ws = (char*)d_ws;
  size_t off = 0;
  off += 32768;  // front pad (64 rows) for Hb window reads at t0=0
  u16* Hb = (u16*)(ws + off);  off += (size_t)BB * TT * DD * 2;
  u16* HG = (u16*)(ws + off);  off += (size_t)BB * TT * DD * 2;
  off += 4096;   // front pad for CWT window reads
  u16* CWT = (u16*)(ws + off); off += (size_t)BB * TT * DD * 2;
  int* rws = (int*)(ws + off); off += (size_t)BB * TT * 4;
  int* Rws = (int*)(ws + off); off += 1024;
  u16* WT = (u16*)(ws + off);  off += (size_t)512 * 256 * 2;
  u16* WcTb = (u16*)(ws + off); off += (size_t)256 * 256 * 2;
  float* bco = (float*)(ws + off); off += 1024;
  float* WqT = (float*)(ws + off);  off += (size_t)256 * 256 * 4;
  float* WcTf = (float*)(ws + off); off += (size_t)256 * 256 * 4;

  prep0<<<161, 256, 0, stream>>>(masks, Wq, Wc, Wo, bc,
                                 WqT, WcTf, WcTb, bco, rws, Rws, out_ptr);
  front2<<<1536, 256, 0, stream>>>(H, Wc, Wo, WqT, WcTf, Hb, WT);
  gemm2<<<4096, 256, 0, stream>>>(Hb, WT, bco, HG, CWT);
  attn_mfma<<<2176, 256, 52480, stream>>>(HG, Hb, CWT, rws, bo, out_read,
                                          Hb, WcTb, bc, Rws, out_buf);
}

// Round 15
// 180.547 us; speedup vs baseline: 1.0668x; 1.0668x over previous
//
#include <hip/hip_runtime.h>
#include <hip/hip_bf16.h>
#include <cstdint>

#define BB 128
#define TT 1024
#define DD 256
#define NN 64
#define SCALE 0.0625f   // 1/sqrt(256)

using u16 = unsigned short;
using u32 = unsigned int;

typedef __attribute__((ext_vector_type(8))) short bf16x8;
typedef __attribute__((ext_vector_type(4))) float f32x4;

typedef const __attribute__((address_space(1))) u32 gbl_u32;
typedef __attribute__((address_space(3))) u32 lds_u32;

__device__ __forceinline__ u16 f2bf(float f) {
  u32 u = __float_as_uint(f);
  u32 r = (u + 0x7fffu + ((u >> 16) & 1u)) >> 16;  // RNE
  return (u16)r;
}

// async 16B global->LDS. LDS base must be wave-uniform; lane i lands at +i*16.
__device__ __forceinline__ void gload16(const void* g, void* l) {
  __builtin_amdgcn_global_load_lds((gbl_u32*)g, (lds_u32*)l, 16, 0, 0);
}

// ---- K0: prep0 — coalesced transposes + mask scan + bco.
__global__ __launch_bounds__(256) void prep0(
    const float* __restrict__ masks, const float* __restrict__ Wq,
    const float* __restrict__ Wc, const float* __restrict__ Wo,
    const float* __restrict__ bc,
    float* __restrict__ WqT, float* __restrict__ WcTf, u16* __restrict__ WcTb,
    float* __restrict__ bco, int* __restrict__ r, int* __restrict__ Rfin,
    float* __restrict__ ptr_out) {
  __shared__ __align__(16) float lds[64 * 65];
  const int bid = blockIdx.x;
  const int tid = threadIdx.x;

  if (bid < 128) {  // mask scan
    int* sm = (int*)lds;
    int b = bid;
    int t4 = tid * 4;
    int v[4], pm[4];
#pragma unroll
    for (int j = 0; j < 4; ++j) {
      float m = masks[b * TT + t4 + j];
      v[j] = (m == 0.0f) ? (t4 + j) : 0;
    }
    pm[0] = v[0];
    pm[1] = max(pm[0], v[1]);
    pm[2] = max(pm[1], v[2]);
    pm[3] = max(pm[2], v[3]);
    sm[tid] = pm[3];
    __syncthreads();
    for (int off = 1; off < 256; off <<= 1) {
      int u = (tid >= off) ? sm[tid - off] : 0;
      __syncthreads();
      sm[tid] = max(sm[tid], u);
      __syncthreads();
    }
    int excl = (tid > 0) ? sm[tid - 1] : 0;
#pragma unroll
    for (int j = 0; j < 4; ++j) r[b * TT + t4 + j] = max(excl, pm[j]);
    if (tid == 255) {
      int R = max(excl, pm[3]);
      Rfin[b] = R;
      ptr_out[b] = (float)((TT - R) & (NN - 1));
    }
    return;
  }

  if (bid < 160) {  // transpose tiles
    int t = bid - 128;
    int mat = t >> 4;          // 0: Wq, 1: Wc
    int tile = t & 15;
    int R0 = (tile >> 2) * 64, C0 = (tile & 3) * 64;
    const float* src = (mat == 0) ? Wq : Wc;
#pragma unroll
    for (int i = 0; i < 4; ++i) {
      int idx = i * 256 + tid;
      int row = idx >> 4, cu = (idx & 15) << 2;
      float4 v = *(const float4*)(src + (size_t)(R0 + row) * 256 + C0 + cu);
      *(float4*)(lds + row * 65 + cu) = v;
    }
    __syncthreads();
#pragma unroll
    for (int i = 0; i < 4; ++i) {
      int idx = i * 256 + tid;
      int col = idx >> 4, ru = (idx & 15) << 2;
      float4 o;
      o.x = lds[(ru + 0) * 65 + col];
      o.y = lds[(ru + 1) * 65 + col];
      o.z = lds[(ru + 2) * 65 + col];
      o.w = lds[(ru + 3) * 65 + col];
      size_t dsti = (size_t)(C0 + col) * 256 + R0 + ru;
      if (mat == 0) {
        *(float4*)(WqT + dsti) = o;
      } else {
        *(float4*)(WcTf + dsti) = o;
        ushort4 p;
        p.x = f2bf(o.x); p.y = f2bf(o.y); p.z = f2bf(o.z); p.w = f2bf(o.w);
        *(ushort4*)(WcTb + dsti) = p;
      }
    }
    return;
  }

  {  // bco
    int k = tid;
    float acc = 0.f;
    for (int d = 0; d < 256; ++d)
      acc = fmaf(bc[d], Wo[d * 256 + k], acc);
    bco[k] = acc;
  }
}

// ---- K1: front2 — weight GEMMs (coalesced VALU) + h2bf.
__global__ __launch_bounds__(256) void front2(
    const float* __restrict__ H, const float* __restrict__ Wc,
    const float* __restrict__ Wo, const float* __restrict__ WqT,
    const float* __restrict__ WcTf, u16* __restrict__ Hb,
    u16* __restrict__ WT) {
  const int bid = blockIdx.x;
  const int tid = threadIdx.x;

  if (bid < 256) {  // Gt row n
    int n = bid, k = tid;
    float a0 = 0.f, a1 = 0.f, a2 = 0.f, a3 = 0.f;
    for (int d = 0; d < 256; d += 4) {
      float4 wv = *(const float4*)(Wc + n * 256 + d);  // wave-uniform
      a0 = fmaf(wv.x, WqT[(size_t)(d + 0) * 256 + k], a0);
      a1 = fmaf(wv.y, WqT[(size_t)(d + 1) * 256 + k], a1);
      a2 = fmaf(wv.z, WqT[(size_t)(d + 2) * 256 + k], a2);
      a3 = fmaf(wv.w, WqT[(size_t)(d + 3) * 256 + k], a3);
    }
    WT[(size_t)n * 256 + k] = f2bf((a0 + a1) + (a2 + a3));
    return;
  }

  if (bid < 512) {  // WcoT row n
    int n = bid - 256, k = tid;
    float a0 = 0.f, a1 = 0.f, a2 = 0.f, a3 = 0.f;
    for (int d = 0; d < 256; d += 4) {
      float w0 = Wo[(size_t)(d + 0) * 256 + n];  // wave-uniform scalars
      float w1 = Wo[(size_t)(d + 1) * 256 + n];
      float w2 = Wo[(size_t)(d + 2) * 256 + n];
      float w3 = Wo[(size_t)(d + 3) * 256 + n];
      a0 = fmaf(w0, WcTf[(size_t)(d + 0) * 256 + k], a0);
      a1 = fmaf(w1, WcTf[(size_t)(d + 1) * 256 + k], a1);
      a2 = fmaf(w2, WcTf[(size_t)(d + 2) * 256 + k], a2);
      a3 = fmaf(w3, WcTf[(size_t)(d + 3) * 256 + k], a3);
    }
    WT[(size_t)(256 + n) * 256 + k] = f2bf((a0 + a1) + (a2 + a3));
    return;
  }

  {  // h2bf: 128 rows/block
    size_t base = (size_t)(bid - 512) * 128 * 256;
#pragma unroll
    for (int i = 0; i < 16; ++i) {
      size_t e = base + ((size_t)(i * 256 + tid)) * 8;
      float4 a = *(const float4*)(H + e);
      float4 b = *(const float4*)(H + e + 4);
      uint4 p;
      p.x = (u32)f2bf(a.x) | ((u32)f2bf(a.y) << 16);
      p.y = (u32)f2bf(a.z) | ((u32)f2bf(a.w) << 16);
      p.z = (u32)f2bf(b.x) | ((u32)f2bf(b.y) << 16);
      p.w = (u32)f2bf(b.z) | ((u32)f2bf(b.w) << 16);
      *(uint4*)(Hb + e) = p;
    }
  }
}

// ---- K2: MFMA GEMM, BM=64 (R13-proven config, 4096 blocks).
// CWT now TILE-BLOCKED: CWT[(xb*256 + d)*64 + ml] — each block's CWT
// epilogue writes one fully-contiguous 32KB chunk (was: 256 x 128B strips
// 256KB apart -> HBM row thrash, measured ~45% of achievable write BW).
__global__ __launch_bounds__(256, 2) void gemm2(
    const u16* __restrict__ Hb, const u16* __restrict__ WT,
    const float* __restrict__ bco,
    u16* __restrict__ HG, u16* __restrict__ CWT) {
  __shared__ __align__(16) char smem[40960];
  u16* As = (u16*)smem;             // [64][64]; unit p holds global unit p^(row&7)
  u16* Bs = (u16*)(smem + 8192);    // [256][64], same swizzle in n
  const int tid = threadIdx.x;
  const int bid = blockIdx.x;
  const int chunk = bid >> 4, jj8 = bid & 15;
  const int xb = chunk * 8 + (jj8 & 7);   // 0..2047
  const int ntb = jj8 >> 3;
  const int M0 = xb * 64;
  const int N0 = ntb * 256;
  const int w = tid >> 6, l = tid & 63;
  const int l15 = l & 15, g = l >> 4;

  f32x4 acc[4][4];
#pragma unroll
  for (int i = 0; i < 4; ++i)
#pragma unroll
    for (int j = 0; j < 4; ++j) acc[i][j] = f32x4{0.f, 0.f, 0.f, 0.f};

  for (int kt = 0; kt < 4; ++kt) {
    __syncthreads();
    // stage B: 2048 16B-units, 8/thread
#pragma unroll
    for (int i = 0; i < 8; ++i) {
      int q = i * 256 + w * 64 + l;
      int n = q >> 3, u = q & 7;
      const u16* src = WT + (size_t)(N0 + n) * 256 + kt * 64 + ((u ^ (n & 7)) << 3);
      gload16(src, Bs + (size_t)(i * 256 + w * 64) * 8);
    }
    // stage A: 512 16B-units (64 rows), 2/thread
#pragma unroll
    for (int i = 0; i < 2; ++i) {
      int q = i * 256 + w * 64 + l;
      int row = q >> 3, u = q & 7;
      const u16* src = Hb + (size_t)(M0 + row) * 256 + kt * 64 + ((u ^ (row & 7)) << 3);
      gload16(src, As + (size_t)(i * 256 + w * 64) * 8);
    }
    __syncthreads();
#pragma unroll
    for (int ks = 0; ks < 2; ++ks) {
      bf16x8 af[4];
#pragma unroll
      for (int mt = 0; mt < 4; ++mt) {
        int row = mt * 16 + l15;
        int unit = ks * 4 + g;
        af[mt] = *(const bf16x8*)(As + row * 64 + ((unit ^ (row & 7)) << 3));
      }
#pragma unroll
      for (int nt = 0; nt < 4; ++nt) {
        int n = w * 64 + nt * 16 + l15;
        int unit = ks * 4 + g;
        bf16x8 bfr = *(const bf16x8*)(Bs + n * 64 + ((unit ^ (n & 7)) << 3));
#pragma unroll
        for (int mt = 0; mt < 4; ++mt)
          acc[mt][nt] = __builtin_amdgcn_mfma_f32_16x16x32_bf16(af[mt], bfr, acc[mt][nt], 0, 0, 0);
      }
    }
  }
  __syncthreads();  // staging reads done before smem reuse

  if (ntb == 0) {
    // bf16 bounce [64][264] (stride 264 > 256: alias-free; rows 16B-aligned).
    u16* ep16 = (u16*)smem;
#pragma unroll
    for (int mt = 0; mt < 4; ++mt)
#pragma unroll
      for (int nt = 0; nt < 4; ++nt) {
        int row = mt * 16 + g * 4;
        int col = w * 64 + nt * 16 + l15;
#pragma unroll
        for (int rg = 0; rg < 4; ++rg)
          ep16[(row + rg) * 264 + col] = f2bf(acc[mt][nt][rg]);
      }
    __syncthreads();
#pragma unroll
    for (int i = 0; i < 8; ++i) {
      int c = tid + i * 256;
      int row = c >> 5, c8 = (c & 31) << 3;   // 64 rows x 32 8-elem units
      uint4 pk = *(const uint4*)(ep16 + row * 264 + c8);
      *(uint4*)(HG + (size_t)(M0 + row) * 256 + c8) = pk;
    }
  } else {
    // transposed bounce [256][68] (stride 68: alias-free, 8B-aligned rows)
    u16* epT = (u16*)smem;
    float bcv[4];
#pragma unroll
    for (int nt = 0; nt < 4; ++nt) bcv[nt] = bco[w * 64 + nt * 16 + l15];
#pragma unroll
    for (int mt = 0; mt < 4; ++mt)
#pragma unroll
      for (int nt = 0; nt < 4; ++nt) {
        int d = w * 64 + nt * 16 + l15;
        int m = mt * 16 + g * 4;
#pragma unroll
        for (int rg = 0; rg < 4; ++rg)
          epT[d * 68 + m + rg] = f2bf(acc[mt][nt][rg] + bcv[nt]);
      }
    __syncthreads();
    // blocked store: 32KB contiguous per block, ushort4 (512B/wave-instr)
#pragma unroll
    for (int i = 0; i < 16; ++i) {
      int idx = tid + i * 256;          // 0..4095
      int d = idx >> 4, m4 = (idx & 15) << 2;
      *(ushort4*)(CWT + ((size_t)xb * 256 + d) * 64 + m4) =
          *(const ushort4*)(epT + d * 68 + m4);
    }
  }
}

// ---- K3: MFMA sliding-window attention (blocks 0..2047) + final-buffer
// MFMA (tail blocks 2048..2175). CWT reads now tile-blocked: each wave's
// stage load is 1KB fully contiguous (was 4 x 256B strips 256KB apart).
__global__ __launch_bounds__(256, 3) void attn_mfma(
    const u16* __restrict__ HGp, const u16* __restrict__ Hbp,
    const u16* __restrict__ CWTp, const int* __restrict__ r,
    const float* __restrict__ bo, float* __restrict__ out,
    const u16* __restrict__ Hb0, const u16* __restrict__ WcT,
    const float* __restrict__ bc, const int* __restrict__ Rfin,
    float* __restrict__ outbuf) {
  extern __shared__ __align__(16) char smem[];
  const int bid0 = blockIdx.x;
  const int tid = threadIdx.x;
  const int l = tid & 63, w = tid >> 6;
  const int l15 = l & 15, g = l >> 4;

  if (bid0 >= 2048) {
    // ---------- buf path: buf[b][m][d] = valid ? Hb[t_m]@Wc + bc : 0 ----------
    u16* As_b = (u16*)smem;
    u16* Bs_b = (u16*)(smem + 8192);
    const int b = bid0 - 2048;
    const int R = Rfin[b];

    f32x4 acc[4][4];
#pragma unroll
    for (int i = 0; i < 4; ++i)
#pragma unroll
      for (int j = 0; j < 4; ++j) acc[i][j] = f32x4{0.f, 0.f, 0.f, 0.f};

    for (int kt = 0; kt < 4; ++kt) {
      __syncthreads();
#pragma unroll
      for (int i = 0; i < 2; ++i) {
        int c = tid + i * 256;
        int row = c >> 3, u = c & 7;
        int rem = (TT - 1) - R - row;
        uint4 v = {0, 0, 0, 0};
        if (rem >= 0) {
          int tn = R + row + ((rem >> 6) << 6);
          v = *(const uint4*)(Hb0 + ((size_t)b * TT + tn) * 256 + kt * 64 +
                              ((u ^ (row & 7)) << 3));
        }
        *(uint4*)(As_b + row * 64 + (u << 3)) = v;
      }
#pragma unroll
      for (int i = 0; i < 8; ++i) {
        int c = tid + i * 256;
        int n = c >> 3, u = c & 7;
        uint4 v = *(const uint4*)(WcT + (size_t)n * 256 + kt * 64 + u * 8);
        *(uint4*)(Bs_b + n * 64 + ((u ^ (n & 7)) << 3)) = v;
      }
      __syncthreads();
#pragma unroll
      for (int ks = 0; ks < 2; ++ks) {
        bf16x8 af[4];
#pragma unroll
        for (int mt = 0; mt < 4; ++mt) {
          int row = mt * 16 + l15;
          int unit = ks * 4 + g;
          af[mt] = *(const bf16x8*)(As_b + row * 64 + ((unit ^ (row & 7)) << 3));
        }
#pragma unroll
        for (int nt = 0; nt < 4; ++nt) {
          int n = w * 64 + nt * 16 + l15;
          int unit = ks * 4 + g;
          bf16x8 bfr = *(const bf16x8*)(Bs_b + n * 64 + ((unit ^ (n & 7)) << 3));
#pragma unroll
          for (int mt = 0; mt < 4; ++mt)
            acc[mt][nt] = __builtin_amdgcn_mfma_f32_16x16x32_bf16(af[mt], bfr, acc[mt][nt], 0, 0, 0);
        }
      }
    }

    float bc4[4];
#pragma unroll
    for (int nt = 0; nt < 4; ++nt) bc4[nt] = bc[w * 64 + nt * 16 + l15];
#pragma unroll
    for (int mt = 0; mt < 4; ++mt) {
#pragma unroll
      for (int rg = 0; rg < 4; ++rg) {
        int m = mt * 16 + g * 4 + rg;
        bool valid = ((TT - 1) - R - m) >= 0;
#pragma unroll
        for (int nt = 0; nt < 4; ++nt) {
          int d = w * 64 + nt * 16 + l15;
          float val = valid ? (acc[mt][nt][rg] + bc4[nt]) : 0.0f;
          outbuf[((size_t)b * NN + m) * DD + d] = val;
        }
      }
    }
    return;
  }

  // ---------- attention path ----------
  u16* reg0 = (u16*)smem;              // [128][136] staging / ob f32[64][132]
  u16* qs = (u16*)(smem + 34816);      // [64][136]; P overlays Q after scores
  u16* ps = qs;
  int* rvs = (int*)(smem + 52224);     // [64]
  // XCD swizzle (T1): each XCD gets 256 consecutive work ids = 16 full batches.
  const int bid = (bid0 & 7) * 256 + (bid0 >> 3);
  const int b = bid >> 4;
  const int t0 = (bid & 15) * 64;
  const long bt = (long)b * TT;

  if (tid < 64) rvs[tid] = r[bt + t0 + tid];

  f32x4 accs[8];
#pragma unroll
  for (int mt = 0; mt < 8; ++mt) accs[mt] = f32x4{0.f, 0.f, 0.f, 0.f};

  for (int kp = 0; kp < 2; ++kp) {
    __syncthreads();
#pragma unroll
    for (int i = 0; i < 8; ++i) {
      int c = tid + i * 256;
      int row = c >> 4, u = c & 15;
      long tp = bt + (t0 - 64 + row);
      uint4 v = *(const uint4*)(Hbp + tp * 256 + kp * 128 + u * 8);
      *(uint4*)(reg0 + row * 136 + u * 8) = v;
    }
#pragma unroll
    for (int i = 0; i < 4; ++i) {
      int c = tid + i * 256;
      int row = c >> 4, u = c & 15;
      uint4 v = *(const uint4*)(HGp + (bt + t0 + row) * 256 + kp * 128 + u * 8);
      *(uint4*)(qs + row * 136 + u * 8) = v;
    }
    __syncthreads();
    __builtin_amdgcn_s_setprio(1);
#pragma unroll
    for (int ks = 0; ks < 4; ++ks) {
      int qrow = w * 16 + l15;
      bf16x8 bq_ = *(const bf16x8*)(qs + qrow * 136 + ks * 32 + g * 8);
#pragma unroll
      for (int mt = 0; mt < 8; ++mt) {
        int crow = mt * 16 + l15;
        bf16x8 ac = *(const bf16x8*)(reg0 + crow * 136 + ks * 32 + g * 8);
        accs[mt] = __builtin_amdgcn_mfma_f32_16x16x32_bf16(ac, bq_, accs[mt], 0, 0, 0);
      }
    }
    __builtin_amdgcn_s_setprio(0);
  }
  __syncthreads();

  const int jj = w * 16 + l15;
  const int rv = rvs[jj];
  const int ibase = g * 4;
  float mx = -3.0e38f;
#pragma unroll
  for (int mt = 0; mt < 8; ++mt) {
#pragma unroll
    for (int rg = 0; rg < 4; ++rg) {
      int i = mt * 16 + ibase + rg;
      int u = i - jj;
      float s;
      if (u >= 0 && u < 64)
        s = ((t0 - 64 + i) >= rv) ? accs[mt][rg] * SCALE : 0.0f;
      else
        s = -3.0e38f;
      accs[mt][rg] = s;
      mx = fmaxf(mx, s);
    }
  }
  mx = fmaxf(mx, __shfl_xor(mx, 16));
  mx = fmaxf(mx, __shfl_xor(mx, 32));
  float den = 0.f;
#pragma unroll
  for (int mt = 0; mt < 8; ++mt) {
#pragma unroll
    for (int rg = 0; rg < 4; ++rg) {
      float s = accs[mt][rg];
      float e = (s > -1.0e37f) ? __expf(s - mx) : 0.0f;
      accs[mt][rg] = e;
      den += e;
    }
  }
  den += __shfl_xor(den, 16);
  den += __shfl_xor(den, 32);
  float inv = 1.0f / den;
#pragma unroll
  for (int mt = 0; mt < 8; ++mt) {
    float wv[4];
#pragma unroll
    for (int rg = 0; rg < 4; ++rg) {
      int i = mt * 16 + ibase + rg;
      int u = i - jj;
      bool ok = (u >= 0) && (u < 64) && ((t0 - 64 + i) >= rv);
      wv[rg] = ok ? accs[mt][rg] * inv : 0.0f;
    }
    u32 p0 = (u32)f2bf(wv[0]) | ((u32)f2bf(wv[1]) << 16);
    u32 p1 = (u32)f2bf(wv[2]) | ((u32)f2bf(wv[3]) << 16);
    *(uint2*)(ps + (size_t)jj * 136 + mt * 16 + ibase) = make_uint2(p0, p1);
  }
  __syncthreads();

  float* ob = (float*)reg0;
  const long xb0 = (bt + t0 - 64) >> 6;  // tile index of window start
  for (int dp = 0; dp < 2; ++dp) {
#pragma unroll
    for (int i = 0; i < 8; ++i) {
      int c = tid + i * 256;               // 0..2047
      int tau = c >> 10, rem = c & 1023;
      int dl = rem >> 3, u = rem & 7;      // d-local 0..127, m8 0..7
      uint4 v = *(const uint4*)(CWTp +
          ((size_t)(xb0 + tau) * 256 + dp * 128 + dl) * 64 + u * 8);
      *(uint4*)(reg0 + dl * 136 + tau * 64 + u * 8) = v;
    }
    __syncthreads();
    f32x4 accp[8];
#pragma unroll
    for (int mt = 0; mt < 8; ++mt) accp[mt] = f32x4{0.f, 0.f, 0.f, 0.f};
    __builtin_amdgcn_s_setprio(1);
#pragma unroll
    for (int ks = 0; ks < 4; ++ks) {
      bf16x8 bp = *(const bf16x8*)(ps + (size_t)(w * 16 + l15) * 136 + ks * 32 + g * 8);
#pragma unroll
      for (int mt = 0; mt < 8; ++mt) {
        bf16x8 av = *(const bf16x8*)(reg0 + (mt * 16 + l15) * 136 + ks * 32 + g * 8);
        accp[mt] = __builtin_amdgcn_mfma_f32_16x16x32_bf16(av, bp, accp[mt], 0, 0, 0);
      }
    }
    __builtin_amdgcn_s_setprio(0);
    __syncthreads();
#pragma unroll
    for (int mt = 0; mt < 8; ++mt) {
      int d0 = mt * 16 + g * 4;
      *(f32x4*)(ob + (size_t)jj * 132 + d0) = accp[mt];
    }
    __syncthreads();
#pragma unroll
    for (int i = 0; i < 8; ++i) {
      int c = tid + i * 256;
      int row = c >> 5, cq = (c & 31) << 2;
      float4 v = *(const float4*)(ob + row * 132 + cq);
      float4 b4 = *(const float4*)(bo + dp * 128 + cq);
      v.x += b4.x; v.y += b4.y; v.z += b4.z; v.w += b4.w;
      *(float4*)(out + (bt + t0 + row) * 256 + dp * 128 + cq) = v;
    }
    __syncthreads();
  }
}

extern "C" void kernel_launch(void* const* d_in, const int* in_sizes, int n_in,
                              void* d_out, int out_size, void* d_ws, size_t ws_size,
                              hipStream_t stream) {
  const float* H = (const float*)d_in[0];
  const float* masks = (const float*)d_in[1];
  const float* Wq = (const float*)d_in[3];
  const float* Wo = (const float*)d_in[5];
  const float* bo = (const float*)d_in[6];
  const float* Wc = (const float*)d_in[7];
  const float* bc = (const float*)d_in[8];

  float* out = (float*)d_out;
  float* out_read = out;
  float* out_buf = out + (size_t)BB * TT * DD;
  float* out_ptr = out_buf + (size_t)BB * NN * DD;

  char* ws = (char*)d_ws;
  size_t off = 0;
  off += 32768;  // front pad (64 rows) for Hb window reads at t0=0
  u16* Hb = (u16*)(ws + off);  off += (size_t)BB * TT * DD * 2;
  u16* HG = (u16*)(ws + off);  off += (size_t)BB * TT * DD * 2;
  off += 32768;  // front pad for CWT blocked reads (1 tile) at b=0,t0=0
  u16* CWT = (u16*)(ws + off); off += (size_t)BB * TT * DD * 2;
  int* rws = (int*)(ws + off); off += (size_t)BB * TT * 4;
  int* Rws = (int*)(ws + off); off += 1024;
  u16* WT = (u16*)(ws + off);  off += (size_t)512 * 256 * 2;
  u16* WcTb = (u16*)(ws + off); off += (size_t)256 * 256 * 2;
  float* bco = (float*)(ws + off); off += 1024;
  float* WqT = (float*)(ws + off);  off += (size_t)256 * 256 * 4;
  float* WcTf = (float*)(ws + off); off += (size_t)256 * 256 * 4;

  prep0<<<161, 256, 0, stream>>>(masks, Wq, Wc, Wo, bc,
                                 WqT, WcTf, WcTb, bco, rws, Rws, out_ptr);
  front2<<<1536, 256, 0, stream>>>(H, Wc, Wo, WqT, WcTf, Hb, WT);
  gemm2<<<4096, 256, 0, stream>>>(Hb, WT, bco, HG, CWT);
  attn_mfma<<<2176, 256, 52480, stream>>>(HG, Hb, CWT, rws, bo, out_read,
                                          Hb, WcTb, bc, Rws, out_buf);
}